// Round 2
// 632.373 us; speedup vs baseline: 1.0006x; 1.0006x over previous
//
#include <hip/hip_runtime.h>
#include <hip/hip_bf16.h>

typedef __bf16 bf16;
typedef __attribute__((ext_vector_type(8))) __bf16 bf16x8;
typedef __attribute__((ext_vector_type(4))) float f32x4;

constexpr int N_NODES   = 100000;
constexpr int N_PAD     = 100032;   // multiple of 64 (GEMM block tile)
constexpr int D         = 128;
constexpr int D_FF      = 256;
constexpr int N_CLASSES = 26;
constexpr int N_GRAPHS  = 512;
// R13: NB1=256 keeps bucket-cursor write streams L2-resident.
constexpr int NB1       = 256;                       // partition blocks
constexpr int NBUCK     = (N_NODES + 511) / 512;     // 196 dst-buckets of 512 nodes

__device__ inline float2 bf2f(unsigned u) {
    float lo = __uint_as_float(u << 16);
    float hi = __uint_as_float(u & 0xffff0000u);
    return make_float2(lo, hi);
}

// ---------------- CSR build: atomic-free bucket counting sort ----------------

// P1: per-block LDS histogram over dst buckets (bucket = dst >> 9)
__global__ __launch_bounds__(1024) void p1_hist(const int* __restrict__ edst,
                                                int* __restrict__ gcount, int e) {
    __shared__ int cnt[NBUCK];
    for (int t = threadIdx.x; t < NBUCK; t += 1024) cnt[t] = 0;
    __syncthreads();
    int chunk = (e + NB1 - 1) / NB1;
    int lo = blockIdx.x * chunk;
    int hi = min(e, lo + chunk);
    for (int i = lo + threadIdx.x; i < hi; i += 1024)
        atomicAdd(&cnt[edst[i] >> 9], 1);
    __syncthreads();
    for (int t = threadIdx.x; t < NBUCK; t += 1024)
        gcount[t * NB1 + blockIdx.x] = cnt[t];
}

// R15: scan1 writes EXCLUSIVE-within-chunk prefix directly (no scan3 pass;
// consumers add boff[chunk] on the fly; chunk index == t for p3, == b for p45).
__global__ __launch_bounds__(256) void scan1(const int* __restrict__ in,
                                             int* out, int* bsum, int n) {
    __shared__ int sd[256];
    int i = blockIdx.x * 256 + threadIdx.x;
    int v = (i < n) ? in[i] : 0;
    sd[threadIdx.x] = v; __syncthreads();
    for (int off = 1; off < 256; off <<= 1) {
        int t = (threadIdx.x >= off) ? sd[threadIdx.x - off] : 0;
        __syncthreads();
        sd[threadIdx.x] += t;
        __syncthreads();
    }
    if (i < n) out[i] = sd[threadIdx.x] - v;     // exclusive within chunk
    if (threadIdx.x == 255) bsum[blockIdx.x] = sd[255];
}

// R15 fused misc kernel: block 0 = starts (lower_bound) + scan2 (chunk offsets);
// blocks 1..48 = castWT3 (3x128x128 weight transpose+cast).
__global__ __launch_bounds__(1024) void misc_kernel(const int* __restrict__ bsum,
                                                    int* __restrict__ boff, int nb,
                                                    const int* __restrict__ batch,
                                                    int* __restrict__ starts, int n,
                                                    const float* __restrict__ W0,
                                                    const float* __restrict__ W1,
                                                    const float* __restrict__ W2,
                                                    bf16* __restrict__ WT3) {
    int t = threadIdx.x;
    if (blockIdx.x == 0) {
        // starts[g] = lower_bound(batch, g), g in [0, N_GRAPHS]
        if (t <= N_GRAPHS) {
            int lo = 0, hi = n;
            while (lo < hi) {
                int mid = (lo + hi) >> 1;
                if (batch[mid] < t) lo = mid + 1; else hi = mid;
            }
            starts[t] = lo;
        }
        // scan2: exclusive scan of bsum -> boff
        __shared__ int sd[1024];
        int v = (t < nb) ? bsum[t] : 0;
        sd[t] = v; __syncthreads();
        for (int off = 1; off < 1024; off <<= 1) {
            int x = (t >= off) ? sd[t - off] : 0;
            __syncthreads();
            sd[t] += x;
            __syncthreads();
        }
        if (t < nb) boff[t] = sd[t] - v;  // exclusive
    } else {
        int idx = (blockIdx.x - 1) * 1024 + t;     // 0 .. 49151 == 3*128*128
        int l = idx >> 14;
        int rem = idx & 16383;
        int nn = rem >> 7;
        int kk = rem & 127;
        const float* W = (l == 0) ? W0 : (l == 1) ? W1 : W2;
        WT3[idx] = (bf16)W[kk * D + nn];           // WT3[l][n][k] = W[k][n]
    }
}

// P3: scatter edges into bucket-contiguous ebuf; pack (src<<9)|(dst&511)
__global__ __launch_bounds__(1024) void p3_scatter(const int* __restrict__ esrc,
                                                   const int* __restrict__ edst,
                                                   const int* __restrict__ gbase,
                                                   const int* __restrict__ boff,
                                                   int* __restrict__ ebuf, int e) {
    __shared__ int cur[NBUCK];
    for (int t = threadIdx.x; t < NBUCK; t += 1024)
        cur[t] = gbase[t * NB1 + blockIdx.x] + boff[t];   // (t*256+b)>>8 == t
    __syncthreads();
    int chunk = (e + NB1 - 1) / NB1;
    int lo = blockIdx.x * chunk;
    int hi = min(e, lo + chunk);
    for (int i = lo + threadIdx.x; i < hi; i += 1024) {
        int d = edst[i], s = esrc[i];
        int pos = atomicAdd(&cur[d >> 9], 1);   // LDS atomic
        ebuf[pos] = (s << 9) | (d & 511);
    }
}

// P45: fused per-bucket degree count + LDS scan + CSR fill
__global__ __launch_bounds__(1024) void p45_fill(const int* __restrict__ ebuf,
                                                 const int* __restrict__ gbase,
                                                 const int* __restrict__ boff,
                                                 float* __restrict__ dinv,
                                                 int* __restrict__ rowptr,
                                                 int* __restrict__ csrc, int e, int n) {
    __shared__ int cnt[512];
    __shared__ int ps[512];
    __shared__ int cur[512];
    int b = blockIdx.x, t = threadIdx.x;
    if (t < 512) cnt[t] = 0;
    __syncthreads();
    int lo = gbase[b * NB1] + boff[b];                     // (b*256)>>8 == b
    int hi = (b + 1 < NBUCK) ? gbase[(b + 1) * NB1] + boff[b + 1] : e;
    for (int i = lo + t; i < hi; i += 1024)
        atomicAdd(&cnt[ebuf[i] & 511], 1);      // LDS atomic
    __syncthreads();
    int a = (t < 512) ? cnt[t] : 0;
    if (t < 512) ps[t] = a;
    __syncthreads();
    for (int off = 1; off < 512; off <<= 1) {
        int v = (t >= off && t < 512) ? ps[t - off] : 0;
        __syncthreads();
        if (t < 512) ps[t] += v;
        __syncthreads();
    }
    if (t < 512) {
        int g0 = lo + ps[t] - a;             // global CSR slot of node b*512+t
        int node = b * 512 + t;
        cur[t] = g0;
        if (node < n) {
            rowptr[node] = g0;
            dinv[node] = 1.0f / sqrtf((float)(a + 1));   // +1 self-loop
        }
    }
    if (b == 0 && t == 0) rowptr[n] = e;
    __syncthreads();
    for (int i = lo + t; i < hi; i += 1024) {
        int pe = ebuf[i];
        int pos = atomicAdd(&cur[pe & 511], 1);  // LDS atomic
        csrc[pos] = pe >> 9;
    }
}

// ---------------- dense compute ----------------

// R15: C[row][:] = bf16( dinv[row] * (A @ W)[row][:] ) — the gather table
// g[v] = dinv[v]*h[v]; folds the per-edge src weight out of spmm.
__global__ __launch_bounds__(256) void gemm_kernel(const bf16* __restrict__ A,
                                                   const bf16* __restrict__ WT,
                                                   bf16* __restrict__ C,
                                                   const float* __restrict__ dinv, int n) {
    int wave = threadIdx.x >> 6;
    int lane = threadIdx.x & 63;
    int m16  = lane & 15;
    int quad = lane >> 4;
    int row0 = blockIdx.x * 64 + wave * 16;

    bf16x8 a[4];
    const bf16* arow = A + (row0 + m16) * D + quad * 8;
#pragma unroll
    for (int kt = 0; kt < 4; ++kt)
        a[kt] = *(const bf16x8*)(arow + kt * 32);

    float sc[4];
#pragma unroll
    for (int r = 0; r < 4; ++r) {
        int rr = row0 + quad * 4 + r;
        sc[r] = (rr < n) ? dinv[rr] : 0.f;
    }

#pragma unroll
    for (int nt = 0; nt < 8; ++nt) {
        f32x4 acc = {0.f, 0.f, 0.f, 0.f};
        const bf16* brow = WT + (nt * 16 + m16) * D + quad * 8;
#pragma unroll
        for (int kt = 0; kt < 4; ++kt) {
            bf16x8 b = *(const bf16x8*)(brow + kt * 32);
            acc = __builtin_amdgcn_mfma_f32_16x16x32_bf16(a[kt], b, acc, 0, 0, 0);
        }
#pragma unroll
        for (int r = 0; r < 4; ++r)
            C[(row0 + quad * 4 + r) * D + nt * 16 + m16] = (bf16)(sc[r] * acc[r]);
    }
}

// Layer-1 variant: A is f32 (the raw input x); cast to bf16 in-register.
__global__ __launch_bounds__(256) void gemm_f32_kernel(const float* __restrict__ A,
                                                       const bf16* __restrict__ WT,
                                                       bf16* __restrict__ C,
                                                       const float* __restrict__ dinv, int n) {
    int wave = threadIdx.x >> 6;
    int lane = threadIdx.x & 63;
    int m16  = lane & 15;
    int quad = lane >> 4;
    int row0 = blockIdx.x * 64 + wave * 16;
    int arowi = row0 + m16;

    bf16x8 a[4];
    const float* arow = A + (size_t)arowi * D + quad * 8;
#pragma unroll
    for (int kt = 0; kt < 4; ++kt) {
        float4 f0 = make_float4(0.f, 0.f, 0.f, 0.f);
        float4 f1 = make_float4(0.f, 0.f, 0.f, 0.f);
        if (arowi < n) {
            f0 = *(const float4*)(arow + kt * 32);
            f1 = *(const float4*)(arow + kt * 32 + 4);
        }
        bf16x8 v = { (bf16)f0.x, (bf16)f0.y, (bf16)f0.z, (bf16)f0.w,
                     (bf16)f1.x, (bf16)f1.y, (bf16)f1.z, (bf16)f1.w };
        a[kt] = v;
    }

    float sc[4];
#pragma unroll
    for (int r = 0; r < 4; ++r) {
        int rr = row0 + quad * 4 + r;
        sc[r] = (rr < n) ? dinv[rr] : 0.f;
    }

#pragma unroll
    for (int nt = 0; nt < 8; ++nt) {
        f32x4 acc = {0.f, 0.f, 0.f, 0.f};
        const bf16* brow = WT + (nt * 16 + m16) * D + quad * 8;
#pragma unroll
        for (int kt = 0; kt < 4; ++kt) {
            bf16x8 b = *(const bf16x8*)(brow + kt * 32);
            acc = __builtin_amdgcn_mfma_f32_16x16x32_bf16(a[kt], b, acc, 0, 0, 0);
        }
#pragma unroll
        for (int r = 0; r < 4; ++r)
            C[(row0 + quad * 4 + r) * D + nt * 16 + m16] = (bf16)(sc[r] * acc[r]);
    }
}

// R15: table g pre-scaled by dinv[src] (bf16). Inner loop pure gather+add,
// 4-deep gather pipeline (MLP probe: latency-bound -> faster; fabric-bound -> flat).
// out[v][:] = relu( dv * ( g[v] + sum_e g[src] ) + bias ),  dv = dinv[v]
__global__ __launch_bounds__(256) void spmm_kernel(const bf16* __restrict__ h,
                                                   const int* __restrict__ rowptr,
                                                   const int* __restrict__ csrc,
                                                   const float* __restrict__ dinv,
                                                   const float* __restrict__ bias,
                                                   bf16* __restrict__ out, int n) {
    int v = blockIdx.x * 4 + (threadIdx.x >> 6);
    if (v >= n) return;
    int lane = threadIdx.x & 63;
    int g = lane >> 4;          // edge group 0..3
    int c = lane & 15;          // dim chunk: dims c*8 .. c*8+7
    int s = rowptr[v], e = rowptr[v + 1];
    float dv = dinv[v];

    float acc[8] = {0.f, 0.f, 0.f, 0.f, 0.f, 0.f, 0.f, 0.f};

    if (g == 0) {
        uint4 u = *(const uint4*)(h + (size_t)v * D + c * 8);
        float2 f0 = bf2f(u.x), f1 = bf2f(u.y), f2 = bf2f(u.z), f3 = bf2f(u.w);
        acc[0] = f0.x; acc[1] = f0.y; acc[2] = f1.x; acc[3] = f1.y;
        acc[4] = f2.x; acc[5] = f2.y; acc[6] = f3.x; acc[7] = f3.y;
    }

    int j = s + g;
    for (; j + 12 < e; j += 16) {
        int s0 = csrc[j], s1 = csrc[j + 4], s2 = csrc[j + 8], s3 = csrc[j + 12];
        uint4 u0 = *(const uint4*)(h + (size_t)s0 * D + c * 8);
        uint4 u1 = *(const uint4*)(h + (size_t)s1 * D + c * 8);
        uint4 u2 = *(const uint4*)(h + (size_t)s2 * D + c * 8);
        uint4 u3 = *(const uint4*)(h + (size_t)s3 * D + c * 8);
        {
            float2 a0 = bf2f(u0.x), a1 = bf2f(u0.y), a2 = bf2f(u0.z), a3 = bf2f(u0.w);
            acc[0] += a0.x; acc[1] += a0.y; acc[2] += a1.x; acc[3] += a1.y;
            acc[4] += a2.x; acc[5] += a2.y; acc[6] += a3.x; acc[7] += a3.y;
        }
        {
            float2 a0 = bf2f(u1.x), a1 = bf2f(u1.y), a2 = bf2f(u1.z), a3 = bf2f(u1.w);
            acc[0] += a0.x; acc[1] += a0.y; acc[2] += a1.x; acc[3] += a1.y;
            acc[4] += a2.x; acc[5] += a2.y; acc[6] += a3.x; acc[7] += a3.y;
        }
        {
            float2 a0 = bf2f(u2.x), a1 = bf2f(u2.y), a2 = bf2f(u2.z), a3 = bf2f(u2.w);
            acc[0] += a0.x; acc[1] += a0.y; acc[2] += a1.x; acc[3] += a1.y;
            acc[4] += a2.x; acc[5] += a2.y; acc[6] += a3.x; acc[7] += a3.y;
        }
        {
            float2 a0 = bf2f(u3.x), a1 = bf2f(u3.y), a2 = bf2f(u3.z), a3 = bf2f(u3.w);
            acc[0] += a0.x; acc[1] += a0.y; acc[2] += a1.x; acc[3] += a1.y;
            acc[4] += a2.x; acc[5] += a2.y; acc[6] += a3.x; acc[7] += a3.y;
        }
    }
    for (; j < e; j += 4) {
        int s0 = csrc[j];
        uint4 u0 = *(const uint4*)(h + (size_t)s0 * D + c * 8);
        float2 a0 = bf2f(u0.x), a1 = bf2f(u0.y), a2 = bf2f(u0.z), a3 = bf2f(u0.w);
        acc[0] += a0.x; acc[1] += a0.y; acc[2] += a1.x; acc[3] += a1.y;
        acc[4] += a2.x; acc[5] += a2.y; acc[6] += a3.x; acc[7] += a3.y;
    }

#pragma unroll
    for (int d = 0; d < 8; ++d) {
        acc[d] += __shfl_xor(acc[d], 16);
        acc[d] += __shfl_xor(acc[d], 32);
    }

    if (g == 0) {
        float4 bi0 = *(const float4*)(bias + c * 8);
        float4 bi1 = *(const float4*)(bias + c * 8 + 4);
        bf16x8 o;
        o[0] = (bf16)fmaxf(fmaf(dv, acc[0], bi0.x), 0.f);
        o[1] = (bf16)fmaxf(fmaf(dv, acc[1], bi0.y), 0.f);
        o[2] = (bf16)fmaxf(fmaf(dv, acc[2], bi0.z), 0.f);
        o[3] = (bf16)fmaxf(fmaf(dv, acc[3], bi0.w), 0.f);
        o[4] = (bf16)fmaxf(fmaf(dv, acc[4], bi1.x), 0.f);
        o[5] = (bf16)fmaxf(fmaf(dv, acc[5], bi1.y), 0.f);
        o[6] = (bf16)fmaxf(fmaf(dv, acc[6], bi1.z), 0.f);
        o[7] = (bf16)fmaxf(fmaf(dv, acc[7], bi1.w), 0.f);
        *(bf16x8*)(out + v * D + c * 8) = o;
    }
}

// fused mean-pool + 2-layer FC head: one block per graph.
// R15: FC1 4-way accumulator split; FC2 parallel over 26x8 threads (was a
// 256-deep serial fmaf chain on 26 threads at 2 blocks/CU — latency-bound).
__global__ __launch_bounds__(256) void poolfc_kernel(const bf16* __restrict__ h,
                                                     const int* __restrict__ starts,
                                                     const float* __restrict__ Wfc,
                                                     const float* __restrict__ bfc,
                                                     const float* __restrict__ Wfc2,
                                                     const float* __restrict__ bfc2,
                                                     float* __restrict__ out) {
    __shared__ float part[3][D];
    __shared__ float pr[D];
    __shared__ float hid[D_FF];
    __shared__ float red[N_CLASSES][9];
    int g = blockIdx.x;
    int w = threadIdx.x >> 6, lane = threadIdx.x & 63;
    int s = starts[g], e = starts[g + 1];
    float ax = 0.f, ay = 0.f;
    for (int r = s + w; r < e; r += 4) {
        unsigned u = *(const unsigned*)(h + r * D + lane * 2);
        float2 f = bf2f(u);
        ax += f.x; ay += f.y;
    }
    if (w > 0) { part[w - 1][lane * 2] = ax; part[w - 1][lane * 2 + 1] = ay; }
    __syncthreads();
    if (w == 0) {
#pragma unroll
        for (int k = 0; k < 3; ++k) { ax += part[k][lane * 2]; ay += part[k][lane * 2 + 1]; }
        float c = fmaxf((float)(e - s), 1.0f);
        pr[lane * 2]     = ax / c;
        pr[lane * 2 + 1] = ay / c;
    }
    __syncthreads();
    int t = threadIdx.x;
    float a0 = 0.f, a1 = 0.f, a2 = 0.f, a3 = 0.f;
    for (int k = 0; k < D; k += 4) {
        a0 = fmaf(pr[k],     Wfc[k * D_FF + t],       a0);
        a1 = fmaf(pr[k + 1], Wfc[(k + 1) * D_FF + t], a1);
        a2 = fmaf(pr[k + 2], Wfc[(k + 2) * D_FF + t], a2);
        a3 = fmaf(pr[k + 3], Wfc[(k + 3) * D_FF + t], a3);
    }
    hid[t] = fmaxf((a0 + a1) + (a2 + a3) + bfc[t], 0.f);
    __syncthreads();
    if (t < N_CLASSES * 8) {
        int cls = t >> 3, kk = t & 7;
        float o = 0.f;
        for (int k = kk; k < D_FF; k += 8)
            o = fmaf(hid[k], Wfc2[k * N_CLASSES + cls], o);
        red[cls][kk] = o;
    }
    __syncthreads();
    if (t < N_CLASSES) {
        float o = bfc2[t];
#pragma unroll
        for (int k = 0; k < 8; ++k) o += red[t][k];
        out[g * N_CLASSES + t] = o;
    }
}

// ---------------- launch ----------------

extern "C" void kernel_launch(void* const* d_in, const int* in_sizes, int n_in,
                              void* d_out, int out_size, void* d_ws, size_t ws_size,
                              hipStream_t stream) {
    const float* x     = (const float*)d_in[0];
    const int*   eidx  = (const int*)d_in[1];
    const int*   batch = (const int*)d_in[2];
    const float* W[3]  = { (const float*)d_in[3], (const float*)d_in[5], (const float*)d_in[7] };
    const float* b[3]  = { (const float*)d_in[4], (const float*)d_in[6], (const float*)d_in[8] };
    const float* Wfc   = (const float*)d_in[9];
    const float* bfc   = (const float*)d_in[10];
    const float* Wfc2  = (const float*)d_in[11];
    const float* bfc2  = (const float*)d_in[12];
    float* out = (float*)d_out;

    const int E = in_sizes[1] / 2;           // 3,200,000
    const int N = in_sizes[0] / D;           // 100,000
    const int* esrc = eidx;
    const int* edst = eidx + E;

    uint8_t* base = (uint8_t*)d_ws;
    size_t off = 0;
    auto alloc = [&](size_t bytes) -> void* {
        void* p = base + off;
        off = (off + bytes + 255) & ~(size_t)255;
        return p;
    };
    bf16*  hA     = (bf16*) alloc((size_t)N_PAD * D * 2);   // bf16 gather table
    bf16*  hB     = (bf16*) alloc((size_t)N_PAD * D * 2);
    bf16*  WT3    = (bf16*) alloc((size_t)3 * D * D * 2);
    int*   csrc   = (int*)  alloc((size_t)E * 4);
    int*   ebuf   = (int*)  alloc((size_t)E * 4);
    int*   gcount = (int*)  alloc((size_t)NBUCK * NB1 * 4);
    int*   gbase  = (int*)  alloc((size_t)(NBUCK * NB1 + 1) * 4);
    int*   rowptr = (int*)  alloc((size_t)(N + 1) * 4);
    float* dinv   = (float*)alloc((size_t)N * 4);
    int*   bsum   = (int*)  alloc(4096);
    int*   boff   = (int*)  alloc(4096);
    int*   starts = (int*)  alloc((size_t)(N_GRAPHS + 1) * 4);
    (void)ws_size; (void)n_in; (void)out_size;

    const int GB  = N_PAD / 64;                         // 1563
    const int SB  = (N + 3) / 4;                        // spmm blocks
    const int GCN = NBUCK * NB1;                        // 50176
    const int GCB = (GCN + 255) / 256;                  // 196

    // CSR build (atomic-free, LDS counting sort)
    p1_hist<<<NB1, 1024, 0, stream>>>(edst, gcount, E);
    scan1<<<GCB, 256, 0, stream>>>(gcount, gbase, bsum, GCN);
    // fused: scan2 + starts + weight transpose/cast
    misc_kernel<<<49, 1024, 0, stream>>>(bsum, boff, GCB, batch, starts, N,
                                         W[0], W[1], W[2], WT3);
    p3_scatter<<<NB1, 1024, 0, stream>>>(esrc, edst, gbase, boff, ebuf, E);
    p45_fill<<<NBUCK, 1024, 0, stream>>>(ebuf, gbase, boff, dinv, rowptr, csrc, E, N);

    // layer 1 (f32 input, in-register cast), then layers 2-3
    gemm_f32_kernel<<<GB, 256, 0, stream>>>(x, WT3, hA, dinv, N);
    spmm_kernel<<<SB, 256, 0, stream>>>(hA, rowptr, csrc, dinv, b[0], hB, N);
    for (int l = 1; l < 3; ++l) {
        gemm_kernel<<<GB, 256, 0, stream>>>(hB, WT3 + (size_t)l * D * D, hA, dinv, N);
        spmm_kernel<<<SB, 256, 0, stream>>>(hA, rowptr, csrc, dinv, b[l], hB, N);
    }

    // fused mean-pool + FC head
    poolfc_kernel<<<N_GRAPHS, 256, 0, stream>>>(hB, starts, Wfc, bfc, Wfc2, bfc2, out);
}

// Round 3
// 580.624 us; speedup vs baseline: 1.0898x; 1.0891x over previous
//
#include <hip/hip_runtime.h>
#include <hip/hip_bf16.h>

typedef __bf16 bf16;
typedef __attribute__((ext_vector_type(8))) __bf16 bf16x8;
typedef __attribute__((ext_vector_type(4))) float f32x4;

constexpr int N_NODES   = 100000;
constexpr int N_PAD     = 100032;   // multiple of 64 (GEMM block tile)
constexpr int D         = 128;
constexpr int D_FF      = 256;
constexpr int N_CLASSES = 26;
constexpr int N_GRAPHS  = 512;
// R13: NB1=256 keeps bucket-cursor write streams L2-resident.
constexpr int NB1       = 256;                       // partition blocks
constexpr int NBUCK     = (N_NODES + 511) / 512;     // 196 dst-buckets of 512 nodes

__device__ inline float2 bf2f(unsigned u) {
    float lo = __uint_as_float(u << 16);
    float hi = __uint_as_float(u & 0xffff0000u);
    return make_float2(lo, hi);
}

// ---------------- CSR build: atomic-free bucket counting sort ----------------

// P1: per-block LDS histogram over dst buckets (bucket = dst >> 9)
__global__ __launch_bounds__(1024) void p1_hist(const int* __restrict__ edst,
                                                int* __restrict__ gcount, int e) {
    __shared__ int cnt[NBUCK];
    for (int t = threadIdx.x; t < NBUCK; t += 1024) cnt[t] = 0;
    __syncthreads();
    int chunk = (e + NB1 - 1) / NB1;
    int lo = blockIdx.x * chunk;
    int hi = min(e, lo + chunk);
    for (int i = lo + threadIdx.x; i < hi; i += 1024)
        atomicAdd(&cnt[edst[i] >> 9], 1);
    __syncthreads();
    for (int t = threadIdx.x; t < NBUCK; t += 1024)
        gcount[t * NB1 + blockIdx.x] = cnt[t];
}

// R15: scan1 writes EXCLUSIVE-within-chunk prefix directly (no scan3 pass;
// consumers add boff[chunk] on the fly; chunk index == t for p3, == b for p45).
__global__ __launch_bounds__(256) void scan1(const int* __restrict__ in,
                                             int* out, int* bsum, int n) {
    __shared__ int sd[256];
    int i = blockIdx.x * 256 + threadIdx.x;
    int v = (i < n) ? in[i] : 0;
    sd[threadIdx.x] = v; __syncthreads();
    for (int off = 1; off < 256; off <<= 1) {
        int t = (threadIdx.x >= off) ? sd[threadIdx.x - off] : 0;
        __syncthreads();
        sd[threadIdx.x] += t;
        __syncthreads();
    }
    if (i < n) out[i] = sd[threadIdx.x] - v;     // exclusive within chunk
    if (threadIdx.x == 255) bsum[blockIdx.x] = sd[255];
}

// R15 fused misc kernel: block 0 = starts (lower_bound) + scan2 (chunk offsets);
// blocks 1..48 = castWT3 (3x128x128 weight transpose+cast).
__global__ __launch_bounds__(1024) void misc_kernel(const int* __restrict__ bsum,
                                                    int* __restrict__ boff, int nb,
                                                    const int* __restrict__ batch,
                                                    int* __restrict__ starts, int n,
                                                    const float* __restrict__ W0,
                                                    const float* __restrict__ W1,
                                                    const float* __restrict__ W2,
                                                    bf16* __restrict__ WT3) {
    int t = threadIdx.x;
    if (blockIdx.x == 0) {
        // starts[g] = lower_bound(batch, g), g in [0, N_GRAPHS]
        if (t <= N_GRAPHS) {
            int lo = 0, hi = n;
            while (lo < hi) {
                int mid = (lo + hi) >> 1;
                if (batch[mid] < t) lo = mid + 1; else hi = mid;
            }
            starts[t] = lo;
        }
        // scan2: exclusive scan of bsum -> boff
        __shared__ int sd[1024];
        int v = (t < nb) ? bsum[t] : 0;
        sd[t] = v; __syncthreads();
        for (int off = 1; off < 1024; off <<= 1) {
            int x = (t >= off) ? sd[t - off] : 0;
            __syncthreads();
            sd[t] += x;
            __syncthreads();
        }
        if (t < nb) boff[t] = sd[t] - v;  // exclusive
    } else {
        int idx = (blockIdx.x - 1) * 1024 + t;     // 0 .. 49151 == 3*128*128
        int l = idx >> 14;
        int rem = idx & 16383;
        int nn = rem >> 7;
        int kk = rem & 127;
        const float* W = (l == 0) ? W0 : (l == 1) ? W1 : W2;
        WT3[idx] = (bf16)W[kk * D + nn];           // WT3[l][n][k] = W[k][n]
    }
}

// P3: scatter edges into bucket-contiguous ebuf; pack (src<<9)|(dst&511)
__global__ __launch_bounds__(1024) void p3_scatter(const int* __restrict__ esrc,
                                                   const int* __restrict__ edst,
                                                   const int* __restrict__ gbase,
                                                   const int* __restrict__ boff,
                                                   int* __restrict__ ebuf, int e) {
    __shared__ int cur[NBUCK];
    for (int t = threadIdx.x; t < NBUCK; t += 1024)
        cur[t] = gbase[t * NB1 + blockIdx.x] + boff[t];   // (t*256+b)>>8 == t
    __syncthreads();
    int chunk = (e + NB1 - 1) / NB1;
    int lo = blockIdx.x * chunk;
    int hi = min(e, lo + chunk);
    for (int i = lo + threadIdx.x; i < hi; i += 1024) {
        int d = edst[i], s = esrc[i];
        int pos = atomicAdd(&cur[d >> 9], 1);   // LDS atomic
        ebuf[pos] = (s << 9) | (d & 511);
    }
}

// P45: fused per-bucket degree count + LDS scan + CSR fill
__global__ __launch_bounds__(1024) void p45_fill(const int* __restrict__ ebuf,
                                                 const int* __restrict__ gbase,
                                                 const int* __restrict__ boff,
                                                 float* __restrict__ dinv,
                                                 int* __restrict__ rowptr,
                                                 int* __restrict__ csrc, int e, int n) {
    __shared__ int cnt[512];
    __shared__ int ps[512];
    __shared__ int cur[512];
    int b = blockIdx.x, t = threadIdx.x;
    if (t < 512) cnt[t] = 0;
    __syncthreads();
    int lo = gbase[b * NB1] + boff[b];                     // (b*256)>>8 == b
    int hi = (b + 1 < NBUCK) ? gbase[(b + 1) * NB1] + boff[b + 1] : e;
    for (int i = lo + t; i < hi; i += 1024)
        atomicAdd(&cnt[ebuf[i] & 511], 1);      // LDS atomic
    __syncthreads();
    int a = (t < 512) ? cnt[t] : 0;
    if (t < 512) ps[t] = a;
    __syncthreads();
    for (int off = 1; off < 512; off <<= 1) {
        int v = (t >= off && t < 512) ? ps[t - off] : 0;
        __syncthreads();
        if (t < 512) ps[t] += v;
        __syncthreads();
    }
    if (t < 512) {
        int g0 = lo + ps[t] - a;             // global CSR slot of node b*512+t
        int node = b * 512 + t;
        cur[t] = g0;
        if (node < n) {
            rowptr[node] = g0;
            dinv[node] = 1.0f / sqrtf((float)(a + 1));   // +1 self-loop
        }
    }
    if (b == 0 && t == 0) rowptr[n] = e;
    __syncthreads();
    for (int i = lo + t; i < hi; i += 1024) {
        int pe = ebuf[i];
        int pos = atomicAdd(&cur[pe & 511], 1);  // LDS atomic
        csrc[pos] = pe >> 9;
    }
}

// ---------------- dense compute ----------------

// Layer-1: C[row][:] = bf16( dinv[row] * ((f32)A @ W)[row][:] ) — gather table g1.
__global__ __launch_bounds__(256) void gemm_f32_kernel(const float* __restrict__ A,
                                                       const bf16* __restrict__ WT,
                                                       bf16* __restrict__ C,
                                                       const float* __restrict__ dinv, int n) {
    int wave = threadIdx.x >> 6;
    int lane = threadIdx.x & 63;
    int m16  = lane & 15;
    int quad = lane >> 4;
    int row0 = blockIdx.x * 64 + wave * 16;
    int arowi = row0 + m16;

    bf16x8 a[4];
    const float* arow = A + (size_t)arowi * D + quad * 8;
#pragma unroll
    for (int kt = 0; kt < 4; ++kt) {
        float4 f0 = make_float4(0.f, 0.f, 0.f, 0.f);
        float4 f1 = make_float4(0.f, 0.f, 0.f, 0.f);
        if (arowi < n) {
            f0 = *(const float4*)(arow + kt * 32);
            f1 = *(const float4*)(arow + kt * 32 + 4);
        }
        bf16x8 v = { (bf16)f0.x, (bf16)f0.y, (bf16)f0.z, (bf16)f0.w,
                     (bf16)f1.x, (bf16)f1.y, (bf16)f1.z, (bf16)f1.w };
        a[kt] = v;
    }

    float sc[4];
#pragma unroll
    for (int r = 0; r < 4; ++r) {
        int rr = row0 + quad * 4 + r;
        sc[r] = (rr < n) ? dinv[rr] : 0.f;
    }

#pragma unroll
    for (int nt = 0; nt < 8; ++nt) {
        f32x4 acc = {0.f, 0.f, 0.f, 0.f};
        const bf16* brow = WT + (nt * 16 + m16) * D + quad * 8;
#pragma unroll
        for (int kt = 0; kt < 4; ++kt) {
            bf16x8 b = *(const bf16x8*)(brow + kt * 32);
            acc = __builtin_amdgcn_mfma_f32_16x16x32_bf16(a[kt], b, acc, 0, 0, 0);
        }
#pragma unroll
        for (int r = 0; r < 4; ++r)
            C[(row0 + quad * 4 + r) * D + nt * 16 + m16] = (bf16)(sc[r] * acc[r]);
    }
}

// ---------------- R16: aggregation core (16 lanes own one node) ----------------
// Block = 256 thr = 16 node-groups; group owns its node's full 128 dims
// (lane c handles dims c*8..c*8+7). No cross-lane reduce; 4-deep unroll x
// 4 groups/wave = 16 outstanding 256B gathers per wave.
// acc = g[v] + sum_e g[src]   (table g pre-scaled by dinv[src])
__device__ inline void agg_node(const bf16* __restrict__ h, int v, int n, int c,
                                const int* __restrict__ rowptr,
                                const int* __restrict__ csrc,
                                const float* __restrict__ dinv,
                                float& dv, float acc[8]) {
    int s = 0, e = 0;
    dv = 0.f;
    if (v < n) { s = rowptr[v]; e = rowptr[v + 1]; dv = dinv[v]; }
#pragma unroll
    for (int d = 0; d < 8; ++d) acc[d] = 0.f;
    if (v < n) {
        uint4 u = *(const uint4*)(h + (size_t)v * D + c * 8);
        float2 f0 = bf2f(u.x), f1 = bf2f(u.y), f2 = bf2f(u.z), f3 = bf2f(u.w);
        acc[0] = f0.x; acc[1] = f0.y; acc[2] = f1.x; acc[3] = f1.y;
        acc[4] = f2.x; acc[5] = f2.y; acc[6] = f3.x; acc[7] = f3.y;
    }
    int j = s;
    for (; j + 3 < e; j += 4) {
        int s0 = csrc[j], s1 = csrc[j + 1], s2 = csrc[j + 2], s3 = csrc[j + 3];
        uint4 u0 = *(const uint4*)(h + (size_t)s0 * D + c * 8);
        uint4 u1 = *(const uint4*)(h + (size_t)s1 * D + c * 8);
        uint4 u2 = *(const uint4*)(h + (size_t)s2 * D + c * 8);
        uint4 u3 = *(const uint4*)(h + (size_t)s3 * D + c * 8);
        {
            float2 a0 = bf2f(u0.x), a1 = bf2f(u0.y), a2 = bf2f(u0.z), a3 = bf2f(u0.w);
            acc[0] += a0.x; acc[1] += a0.y; acc[2] += a1.x; acc[3] += a1.y;
            acc[4] += a2.x; acc[5] += a2.y; acc[6] += a3.x; acc[7] += a3.y;
        }
        {
            float2 a0 = bf2f(u1.x), a1 = bf2f(u1.y), a2 = bf2f(u1.z), a3 = bf2f(u1.w);
            acc[0] += a0.x; acc[1] += a0.y; acc[2] += a1.x; acc[3] += a1.y;
            acc[4] += a2.x; acc[5] += a2.y; acc[6] += a3.x; acc[7] += a3.y;
        }
        {
            float2 a0 = bf2f(u2.x), a1 = bf2f(u2.y), a2 = bf2f(u2.z), a3 = bf2f(u2.w);
            acc[0] += a0.x; acc[1] += a0.y; acc[2] += a1.x; acc[3] += a1.y;
            acc[4] += a2.x; acc[5] += a2.y; acc[6] += a3.x; acc[7] += a3.y;
        }
        {
            float2 a0 = bf2f(u3.x), a1 = bf2f(u3.y), a2 = bf2f(u3.z), a3 = bf2f(u3.w);
            acc[0] += a0.x; acc[1] += a0.y; acc[2] += a1.x; acc[3] += a1.y;
            acc[4] += a2.x; acc[5] += a2.y; acc[6] += a3.x; acc[7] += a3.y;
        }
    }
    for (; j < e; ++j) {
        int s0 = csrc[j];
        uint4 u0 = *(const uint4*)(h + (size_t)s0 * D + c * 8);
        float2 a0 = bf2f(u0.x), a1 = bf2f(u0.y), a2 = bf2f(u0.z), a3 = bf2f(u0.w);
        acc[0] += a0.x; acc[1] += a0.y; acc[2] += a1.x; acc[3] += a1.y;
        acc[4] += a2.x; acc[5] += a2.y; acc[6] += a3.x; acc[7] += a3.y;
    }
}

__device__ inline bf16x8 relu_row(float dv, const float acc[8],
                                  const float* __restrict__ bias, int c) {
    float4 bi0 = *(const float4*)(bias + c * 8);
    float4 bi1 = *(const float4*)(bias + c * 8 + 4);
    bf16x8 o;
    o[0] = (bf16)fmaxf(fmaf(dv, acc[0], bi0.x), 0.f);
    o[1] = (bf16)fmaxf(fmaf(dv, acc[1], bi0.y), 0.f);
    o[2] = (bf16)fmaxf(fmaf(dv, acc[2], bi0.z), 0.f);
    o[3] = (bf16)fmaxf(fmaf(dv, acc[3], bi0.w), 0.f);
    o[4] = (bf16)fmaxf(fmaf(dv, acc[4], bi1.x), 0.f);
    o[5] = (bf16)fmaxf(fmaf(dv, acc[5], bi1.y), 0.f);
    o[6] = (bf16)fmaxf(fmaf(dv, acc[6], bi1.z), 0.f);
    o[7] = (bf16)fmaxf(fmaf(dv, acc[7], bi1.w), 0.f);
    return o;
}

// R16 fused: aggregate layer l (16 nodes/block), relu-tile in LDS, then the
// block's 4 waves multiply by W_{l+1} (MFMA) and write the NEXT gather table
// g' = dinv * (h_l @ W_{l+1}). Removes a standalone gemm + a 51MB round trip.
__global__ __launch_bounds__(256) void spmm_gemm_kernel(const bf16* __restrict__ h,
                                                        const int* __restrict__ rowptr,
                                                        const int* __restrict__ csrc,
                                                        const float* __restrict__ dinv,
                                                        const float* __restrict__ bias,
                                                        const bf16* __restrict__ WT,
                                                        bf16* __restrict__ C, int n) {
    __shared__ bf16 tile[16][136];          // +8 bf16 row pad (bank spread)
    int t = threadIdx.x;
    int grp = t >> 4;                        // node within block
    int c   = t & 15;                        // dim chunk
    int v   = blockIdx.x * 16 + grp;
    float dv, acc[8];
    agg_node(h, v, n, c, rowptr, csrc, dinv, dv, acc);
    *(bf16x8*)(&tile[grp][c * 8]) = relu_row(dv, acc, bias, c);
    __syncthreads();

    // GEMM: A = tile (16x128), B = WT (128x128, [n][k]); wave w does nt=2w,2w+1
    int wave = t >> 6, lane = t & 63;
    int m16 = lane & 15, quad = lane >> 4;
    bf16x8 a[4];
#pragma unroll
    for (int kt = 0; kt < 4; ++kt)
        a[kt] = *(const bf16x8*)(&tile[m16][quad * 8 + kt * 32]);

    int base = blockIdx.x * 16;
    float sc[4];
#pragma unroll
    for (int r = 0; r < 4; ++r) {
        int rr = base + quad * 4 + r;
        sc[r] = (rr < n) ? dinv[rr] : 0.f;
    }

#pragma unroll
    for (int nt2 = 0; nt2 < 2; ++nt2) {
        int nt = wave * 2 + nt2;
        f32x4 accq = {0.f, 0.f, 0.f, 0.f};
        const bf16* brow = WT + (nt * 16 + m16) * D + quad * 8;
#pragma unroll
        for (int kt = 0; kt < 4; ++kt) {
            bf16x8 b = *(const bf16x8*)(brow + kt * 32);
            accq = __builtin_amdgcn_mfma_f32_16x16x32_bf16(a[kt], b, accq, 0, 0, 0);
        }
#pragma unroll
        for (int r = 0; r < 4; ++r)
            C[(size_t)(base + quad * 4 + r) * D + nt * 16 + m16] = (bf16)(sc[r] * accq[r]);
    }
}

// R16 plain last-layer spmm: same 16-lane-per-node aggregation, direct row write.
__global__ __launch_bounds__(256) void spmm2_kernel(const bf16* __restrict__ h,
                                                    const int* __restrict__ rowptr,
                                                    const int* __restrict__ csrc,
                                                    const float* __restrict__ dinv,
                                                    const float* __restrict__ bias,
                                                    bf16* __restrict__ out, int n) {
    int t = threadIdx.x;
    int grp = t >> 4;
    int c   = t & 15;
    int v   = blockIdx.x * 16 + grp;
    float dv, acc[8];
    agg_node(h, v, n, c, rowptr, csrc, dinv, dv, acc);
    if (v < n)
        *(bf16x8*)(out + (size_t)v * D + c * 8) = relu_row(dv, acc, bias, c);
}

// fused mean-pool + 2-layer FC head: one block per graph.
__global__ __launch_bounds__(256) void poolfc_kernel(const bf16* __restrict__ h,
                                                     const int* __restrict__ starts,
                                                     const float* __restrict__ Wfc,
                                                     const float* __restrict__ bfc,
                                                     const float* __restrict__ Wfc2,
                                                     const float* __restrict__ bfc2,
                                                     float* __restrict__ out) {
    __shared__ float part[3][D];
    __shared__ float pr[D];
    __shared__ float hid[D_FF];
    __shared__ float red[N_CLASSES][9];
    int g = blockIdx.x;
    int w = threadIdx.x >> 6, lane = threadIdx.x & 63;
    int s = starts[g], e = starts[g + 1];
    float ax = 0.f, ay = 0.f;
    for (int r = s + w; r < e; r += 4) {
        unsigned u = *(const unsigned*)(h + r * D + lane * 2);
        float2 f = bf2f(u);
        ax += f.x; ay += f.y;
    }
    if (w > 0) { part[w - 1][lane * 2] = ax; part[w - 1][lane * 2 + 1] = ay; }
    __syncthreads();
    if (w == 0) {
#pragma unroll
        for (int k = 0; k < 3; ++k) { ax += part[k][lane * 2]; ay += part[k][lane * 2 + 1]; }
        float c = fmaxf((float)(e - s), 1.0f);
        pr[lane * 2]     = ax / c;
        pr[lane * 2 + 1] = ay / c;
    }
    __syncthreads();
    int t = threadIdx.x;
    float a0 = 0.f, a1 = 0.f, a2 = 0.f, a3 = 0.f;
    for (int k = 0; k < D; k += 4) {
        a0 = fmaf(pr[k],     Wfc[k * D_FF + t],       a0);
        a1 = fmaf(pr[k + 1], Wfc[(k + 1) * D_FF + t], a1);
        a2 = fmaf(pr[k + 2], Wfc[(k + 2) * D_FF + t], a2);
        a3 = fmaf(pr[k + 3], Wfc[(k + 3) * D_FF + t], a3);
    }
    hid[t] = fmaxf((a0 + a1) + (a2 + a3) + bfc[t], 0.f);
    __syncthreads();
    if (t < N_CLASSES * 8) {
        int cls = t >> 3, kk = t & 7;
        float o = 0.f;
        for (int k = kk; k < D_FF; k += 8)
            o = fmaf(hid[k], Wfc2[k * N_CLASSES + cls], o);
        red[cls][kk] = o;
    }
    __syncthreads();
    if (t < N_CLASSES) {
        float o = bfc2[t];
#pragma unroll
        for (int k = 0; k < 8; ++k) o += red[t][k];
        out[g * N_CLASSES + t] = o;
    }
}

// ---------------- launch ----------------

extern "C" void kernel_launch(void* const* d_in, const int* in_sizes, int n_in,
                              void* d_out, int out_size, void* d_ws, size_t ws_size,
                              hipStream_t stream) {
    const float* x     = (const float*)d_in[0];
    const int*   eidx  = (const int*)d_in[1];
    const int*   batch = (const int*)d_in[2];
    const float* W[3]  = { (const float*)d_in[3], (const float*)d_in[5], (const float*)d_in[7] };
    const float* b[3]  = { (const float*)d_in[4], (const float*)d_in[6], (const float*)d_in[8] };
    const float* Wfc   = (const float*)d_in[9];
    const float* bfc   = (const float*)d_in[10];
    const float* Wfc2  = (const float*)d_in[11];
    const float* bfc2  = (const float*)d_in[12];
    float* out = (float*)d_out;

    const int E = in_sizes[1] / 2;           // 3,200,000
    const int N = in_sizes[0] / D;           // 100,000
    const int* esrc = eidx;
    const int* edst = eidx + E;

    uint8_t* base = (uint8_t*)d_ws;
    size_t off = 0;
    auto alloc = [&](size_t bytes) -> void* {
        void* p = base + off;
        off = (off + bytes + 255) & ~(size_t)255;
        return p;
    };
    bf16*  hA     = (bf16*) alloc((size_t)N_PAD * D * 2);   // bf16 gather table
    bf16*  hB     = (bf16*) alloc((size_t)N_PAD * D * 2);
    bf16*  WT3    = (bf16*) alloc((size_t)3 * D * D * 2);
    int*   csrc   = (int*)  alloc((size_t)E * 4);
    int*   ebuf   = (int*)  alloc((size_t)E * 4);
    int*   gcount = (int*)  alloc((size_t)NBUCK * NB1 * 4);
    int*   gbase  = (int*)  alloc((size_t)(NBUCK * NB1 + 1) * 4);
    int*   rowptr = (int*)  alloc((size_t)(N + 1) * 4);
    float* dinv   = (float*)alloc((size_t)N * 4);
    int*   bsum   = (int*)  alloc(4096);
    int*   boff   = (int*)  alloc(4096);
    int*   starts = (int*)  alloc((size_t)(N_GRAPHS + 1) * 4);
    (void)ws_size; (void)n_in; (void)out_size;

    const int GB  = N_PAD / 64;                         // 1563
    const int SGB = N_PAD / 16;                         // 6252 spmm blocks
    const int GCN = NBUCK * NB1;                        // 50176
    const int GCB = (GCN + 255) / 256;                  // 196

    // CSR build (atomic-free, LDS counting sort)
    p1_hist<<<NB1, 1024, 0, stream>>>(edst, gcount, E);
    scan1<<<GCB, 256, 0, stream>>>(gcount, gbase, bsum, GCN);
    // fused: scan2 + starts + weight transpose/cast
    misc_kernel<<<49, 1024, 0, stream>>>(bsum, boff, GCB, batch, starts, N,
                                         W[0], W[1], W[2], WT3);
    p3_scatter<<<NB1, 1024, 0, stream>>>(esrc, edst, gbase, boff, ebuf, E);
    p45_fill<<<NBUCK, 1024, 0, stream>>>(ebuf, gbase, boff, dinv, rowptr, csrc, E, N);

    // layer 1 input-side GEMM: g1 = dinv * (x @ W1)
    gemm_f32_kernel<<<GB, 256, 0, stream>>>(x, WT3, hA, dinv, N);
    // fused layer1-agg + W2: g2 = dinv * (relu(...b1) @ W2)
    spmm_gemm_kernel<<<SGB, 256, 0, stream>>>(hA, rowptr, csrc, dinv, b[0],
                                              WT3 + (size_t)1 * D * D, hB, N);
    // fused layer2-agg + W3: g3 = dinv * (relu(...b2) @ W3)
    spmm_gemm_kernel<<<SGB, 256, 0, stream>>>(hB, rowptr, csrc, dinv, b[1],
                                              WT3 + (size_t)2 * D * D, hA, N);
    // layer 3 plain aggregation -> h3
    spmm2_kernel<<<SGB, 256, 0, stream>>>(hA, rowptr, csrc, dinv, b[2], hB, N);

    // fused mean-pool + FC head
    poolfc_kernel<<<N_GRAPHS, 256, 0, stream>>>(hB, starts, Wfc, bfc, Wfc2, bfc2, out);
}